// Round 5
// baseline (340.087 us; speedup 1.0000x reference)
//
#include <hip/hip_runtime.h>

#define B 32
#define N 512
#define P 8
#define H 300
#define EPSN 1e-12f
#define NT 32
#define NB (N / NT)       // 16
#define SAP 344           // LDS row stride (halfs): 688B, 16B-aligned, 12-dword bank rotation

typedef _Float16 f16x8 __attribute__((ext_vector_type(8)));
typedef float f32x4 __attribute__((ext_vector_type(4)));

// ---------- fused prep: z<P -> A-fragments for (nb,b,p=z); z==P -> W-fragments ----------
// A unit u(blk,p,ht,nt) = (blk*P+p)*20 + ht*2+nt; elem = u*512 + l*8 + j
//   row = nt*16+(l&15), h = ht*32+(l>>4)*8+j   (A pre-scaled by instruction, fp16)
// W fb = (p*10+ht)*20 + kt; elem = fb*512 + l*8 + j; h = ht*32+(l>>4)*8+j, k = kt*16+(l&15)
__global__ __launch_bounds__(256)
void nsm_prep(const float* __restrict__ node_attr,
              const float* __restrict__ instruction,
              const float* __restrict__ W,
              _Float16* __restrict__ afrag,
              _Float16* __restrict__ wfrag)
{
    const int t = threadIdx.x;
    const int z = blockIdx.z;

    if (z == P) {
        // ---- W prep: 1600 fragment blocks over 512 blocks x 4 waves ----
        const int idx = blockIdx.y * NB + blockIdx.x;    // 0..511
        const int fb  = idx * 4 + (t >> 6);
        if (fb >= 1600) return;
        const int lane = t & 63;
        const int p  = fb / 200;
        const int rm = fb % 200;
        const int ht = rm / 20;
        const int kt = rm % 20;
        const int k  = kt * 16 + (lane & 15);
        const int h0 = ht * 32 + (lane >> 4) * 8;
        f16x8 v;
        #pragma unroll
        for (int j = 0; j < 8; ++j) {
            int h = h0 + j;
            float wv = (h < H && k < H) ? W[((size_t)p * H + h) * H + k] : 0.f;
            v[j] = (_Float16)wv;
        }
        *(f16x8*)(wfrag + (size_t)fb * 512 + (size_t)lane * 8) = v;
        return;
    }

    // ---- A prep ----
    __shared__ _Float16 sA[NT * SAP];
    const int nb = blockIdx.x, b = blockIdx.y, p = z;
    const int r  = t >> 3;       // row 0..31
    const int oc = t & 7;        // oct slot 0..7

    const float* srcA = node_attr + ((size_t)((b * N + nb * NT + r) * P + p)) * H;
    const float* ins  = instruction + (size_t)b * H;

    #pragma unroll
    for (int i = 0; i < 5; ++i) {
        int o  = oc + i * 8;     // 0..39
        int h0 = o * 8;
        f16x8 v8;
        #pragma unroll
        for (int j = 0; j < 8; ++j) v8[j] = (_Float16)0.f;
        if (o < 37) {            // h0+7 <= 303? o=36: 295 ok; o<37 covers h<=295
            float4 va = *(const float4*)(srcA + h0);
            float4 vb = *(const float4*)(srcA + h0 + 4);
            float4 sa = *(const float4*)(ins + h0);
            float4 sb = *(const float4*)(ins + h0 + 4);
            v8[0] = (_Float16)(va.x * sa.x); v8[1] = (_Float16)(va.y * sa.y);
            v8[2] = (_Float16)(va.z * sa.z); v8[3] = (_Float16)(va.w * sa.w);
            v8[4] = (_Float16)(vb.x * sb.x); v8[5] = (_Float16)(vb.y * sb.y);
            v8[6] = (_Float16)(vb.z * sb.z); v8[7] = (_Float16)(vb.w * sb.w);
        } else if (o == 37) {    // h 296..299 valid, 300..303 pad
            float4 va = *(const float4*)(srcA + h0);
            float4 sa = *(const float4*)(ins + h0);
            v8[0] = (_Float16)(va.x * sa.x); v8[1] = (_Float16)(va.y * sa.y);
            v8[2] = (_Float16)(va.z * sa.z); v8[3] = (_Float16)(va.w * sa.w);
        }
        *(f16x8*)&sA[r * SAP + h0] = v8;
    }
    __syncthreads();

    const int w = t >> 6, l = t & 63;
    const size_t ub = ((size_t)(b * NB + nb) * P + p) * 20;
    #pragma unroll
    for (int uu = 0; uu < 5; ++uu) {
        int u  = w + uu * 4;     // 0..19
        int ht = u >> 1, nt = u & 1;
        f16x8 v = *(const f16x8*)&sA[(nt * 16 + (l & 15)) * SAP + ht * 32 + (l >> 4) * 8];
        *(f16x8*)(afrag + (ub + u) * 512 + (size_t)l * 8) = v;
    }
}

// ---------- main: barrier-free MFMA with distance-2 register prefetch ----------
__global__ __launch_bounds__(256, 2)
void nsm_scores_mfma(const _Float16* __restrict__ afrag,
                     const _Float16* __restrict__ wfrag,
                     const float* __restrict__ nps,
                     const float* __restrict__ w_state,
                     float* __restrict__ pscore)
{
    const int t  = threadIdx.x;
    const int nb = blockIdx.x;
    const int b  = blockIdx.y;
    const int w  = t >> 6;       // wave: k-range [80w, 80w+80)
    const int l  = t & 63;

    const _Float16* Ab = afrag + ((size_t)(b * NB + nb) * P) * 10240 + (size_t)l * 8;
    const _Float16* Wb = wfrag + (size_t)(w * 5) * 512 + (size_t)l * 8;

    f32x4 S1[2][5], S2[2][5];
    #pragma unroll
    for (int nt = 0; nt < 2; ++nt)
        #pragma unroll
        for (int kt = 0; kt < 5; ++kt) {
            S1[nt][kt] = (f32x4){0.f, 0.f, 0.f, 0.f};
            S2[nt][kt] = (f32x4){0.f, 0.f, 0.f, 0.f};
        }

    // flat step s = p*10 + ht (0..79); A at Ab + s*1024 (+512 for nt=1),
    // W at Wb + s*10240 + kt*512. Double-buffered regs, prefetch distance 2.
    f16x8 abuf[2][2], wbuf[2][5];
    #pragma unroll
    for (int s = 0; s < 2; ++s) {
        abuf[s][0] = *(const f16x8*)(Ab + s * 1024);
        abuf[s][1] = *(const f16x8*)(Ab + s * 1024 + 512);
        #pragma unroll
        for (int kt = 0; kt < 5; ++kt)
            wbuf[s][kt] = *(const f16x8*)(Wb + (size_t)s * 10240 + kt * 512);
    }

    for (int p = 0; p < P; ++p) {
        f32x4 acc[2][5];
        #pragma unroll
        for (int nt = 0; nt < 2; ++nt)
            #pragma unroll
            for (int kt = 0; kt < 5; ++kt)
                acc[nt][kt] = (f32x4){0.f, 0.f, 0.f, 0.f};

        #pragma unroll
        for (int ht = 0; ht < 10; ++ht) {
            const int sl = ht & 1;           // s%2 == ht%2 (10 even)
            #pragma unroll
            for (int kt = 0; kt < 5; ++kt) {
                acc[0][kt] = __builtin_amdgcn_mfma_f32_16x16x32_f16(abuf[sl][0], wbuf[sl][kt], acc[0][kt], 0, 0, 0);
                acc[1][kt] = __builtin_amdgcn_mfma_f32_16x16x32_f16(abuf[sl][1], wbuf[sl][kt], acc[1][kt], 0, 0, 0);
            }
            // prefetch step s+2 into the slot just consumed
            if (ht < 8 || p < 7) {
                const int s2 = p * 10 + ht + 2;
                const _Float16* Ap2 = Ab + (size_t)s2 * 1024;
                const _Float16* Wp2 = Wb + (size_t)s2 * 10240;
                abuf[sl][0] = *(const f16x8*)(Ap2);
                abuf[sl][1] = *(const f16x8*)(Ap2 + 512);
                #pragma unroll
                for (int kt = 0; kt < 5; ++kt)
                    wbuf[sl][kt] = *(const f16x8*)(Wp2 + kt * 512);
            }
        }

        const float sim = nps[b * P + p];
        #pragma unroll
        for (int nt = 0; nt < 2; ++nt)
            #pragma unroll
            for (int kt = 0; kt < 5; ++kt) {
                f32x4 z = acc[nt][kt] * sim;
                S1[nt][kt] += z;
                S2[nt][kt] += z * z;
            }
    }

    // epilogue: normalize over P, elu, dot w_state, reduce over k-16-group,
    // store per-wave partial (no atomics). C/D: col(k)=l&15, row=(l>>4)*4+j.
    #pragma unroll
    for (int nt = 0; nt < 2; ++nt) {
        #pragma unroll
        for (int j = 0; j < 4; ++j) {
            float part = 0.f;
            #pragma unroll
            for (int kt = 0; kt < 5; ++kt) {
                int k = w * 80 + kt * 16 + (l & 15);
                if (k < H) {
                    float s1 = S1[nt][kt][j];
                    float s2 = S2[nt][kt][j];
                    float denom = fmaxf(sqrtf(s2), EPSN);
                    float v = s1 / denom;
                    float e = v > 0.f ? v : expm1f(v);
                    part += e * w_state[k];
                }
            }
            part += __shfl_xor(part, 1, 16);
            part += __shfl_xor(part, 2, 16);
            part += __shfl_xor(part, 4, 16);
            part += __shfl_xor(part, 8, 16);
            if ((l & 15) == 0) {
                int row = nt * 16 + (l >> 4) * 4 + j;
                pscore[(size_t)w * (B * N) + (size_t)b * N + nb * NT + row] = part;
            }
        }
    }
}

// ---------- softmax: sum 4 wave-partials, masked softmax over N ----------
__global__ __launch_bounds__(256)
void nsm_softmax_kernel(const float* __restrict__ pscore,
                        const float* __restrict__ mask,
                        float* __restrict__ out)
{
    __shared__ float redm[4];
    __shared__ float reds[4];
    const int b = blockIdx.x;
    const int t = threadIdx.x;

    float v0 = mask[b * N + t];
    float v1 = mask[b * N + 256 + t];
    #pragma unroll
    for (int w = 0; w < 4; ++w) {
        v0 += pscore[(size_t)w * (B * N) + b * N + t];
        v1 += pscore[(size_t)w * (B * N) + b * N + 256 + t];
    }

    float m = fmaxf(v0, v1);
    m = fmaxf(m, __shfl_xor(m, 1, 64));
    m = fmaxf(m, __shfl_xor(m, 2, 64));
    m = fmaxf(m, __shfl_xor(m, 4, 64));
    m = fmaxf(m, __shfl_xor(m, 8, 64));
    m = fmaxf(m, __shfl_xor(m, 16, 64));
    m = fmaxf(m, __shfl_xor(m, 32, 64));
    const int wave = t >> 6;
    const int lane = t & 63;
    if (lane == 0) redm[wave] = m;
    __syncthreads();
    m = fmaxf(fmaxf(redm[0], redm[1]), fmaxf(redm[2], redm[3]));

    float e0 = expf(v0 - m);
    float e1 = expf(v1 - m);
    float s = e0 + e1;
    s += __shfl_xor(s, 1, 64);
    s += __shfl_xor(s, 2, 64);
    s += __shfl_xor(s, 4, 64);
    s += __shfl_xor(s, 8, 64);
    s += __shfl_xor(s, 16, 64);
    s += __shfl_xor(s, 32, 64);
    if (lane == 0) reds[wave] = s;
    __syncthreads();
    s = reds[0] + reds[1] + reds[2] + reds[3];

    out[b * N + t]       = e0 / s;
    out[b * N + 256 + t] = e1 / s;
}

extern "C" void kernel_launch(void* const* d_in, const int* in_sizes, int n_in,
                              void* d_out, int out_size, void* d_ws, size_t ws_size,
                              hipStream_t stream)
{
    const float* node_attr   = (const float*)d_in[0];
    const float* instruction = (const float*)d_in[2];
    const float* nps         = (const float*)d_in[5];
    const float* node_mask   = (const float*)d_in[6];
    const float* W_node      = (const float*)d_in[7];
    const float* w_state     = (const float*)d_in[8];
    float* out = (float*)d_out;

    _Float16* afrag = (_Float16*)d_ws;                        // 41.9M halfs = 83.9 MB
    _Float16* wfrag = afrag + (size_t)B * NB * P * 20 * 512;  // 0.82M halfs = 1.6 MB
    float*    pscore = (float*)(wfrag + 1600 * 512);          // 4*B*N floats = 256 KB

    nsm_prep<<<dim3(NB, B, P + 1), 256, 0, stream>>>(node_attr, instruction,
                                                     W_node, afrag, wfrag);
    nsm_scores_mfma<<<dim3(NB, B), 256, 0, stream>>>(afrag, wfrag, nps, w_state, pscore);
    nsm_softmax_kernel<<<dim3(B), 256, 0, stream>>>(pscore, node_mask, out);
}